// Round 12
// baseline (331.249 us; speedup 1.0000x reference)
//
#include <hip/hip_runtime.h>
#include <cfloat>
#include <math.h>

namespace {
constexpr int Bn = 4, Cin = 8, Pn = 12000, Nn = 64, Co = 64, Hh = 282, Ww = 282;
constexpr int NPIL  = Bn * Pn;
constexpr int NCELL = Hh * Ww;
constexpr int CHW   = Pn * Nn;
constexpr double CNTD = (double)Bn * Pn * Nn;
constexpr int K1B = 1024;               // momfeat blocks per input
constexpr int WL_CAP = 48000;           // max occupied cells per input
constexpr int APPLY_B = (WL_CAP + 255) / 256;
constexpr int FILL_B = (Bn * Co * NCELL / 4) / 256;   // 19881, exact
constexpr int NEGB = 1024;              // negfix blocks (usually instant-exit)
constexpr int COMPACT_B = (Bn * NCELL + 255) / 256;   // 1243

// Workspace layout (R8's, proven). part (momfeat partials, 360448 B) aliases
// the wlS region: part is read by k1b2_params; the negfix+compact launch
// (which writes wlS/wlM) runs strictly after it in stream order.
constexpr size_t PAR_OFF  = 0;                          // 2*128 floats
constexpr size_t HDR_OFF  = 2048;                       // 8 ints
constexpr size_t WLS_OFF  = 8192;                       // WL_CAP int2
constexpr size_t PART_OFF = WLS_OFF;                    // alias (see above)
constexpr size_t WLM_OFF  = WLS_OFF + (size_t)WL_CAP * 8;    // 392192
constexpr size_t WIN_OFF  = WLM_OFF + (size_t)WL_CAP * 8;    // 776192
constexpr size_t YMAX_OFF = WIN_OFF + (size_t)2 * Bn * NCELL * 4; // 3320960
constexpr size_t WS_NEED  = YMAX_OFF + (size_t)2 * NPIL * 64 * 4; // 27896960

typedef __attribute__((ext_vector_type(8))) float f32x8_t;

// Grid mapping matched to XLA's canonicalization: division by 0.16 becomes
// multiplication by the EXACT reciprocal 6.25 (rcp(0.16f) rounds to 6.25f).
// f32-div differs by ~0.3ulp -> O(1) pillars land one cell off (the 2.62 bug).
__device__ __forceinline__ int cell_of(float xc, float yc) {
  int xg = (int)floorf((xc + 22.0f) * 6.25f);
  int yg = (int)floorf((yc + 22.0f) * 6.25f);
  xg = min(max(xg, 0), Ww - 1);
  yg = min(max(yg, 0), Hh - 1);
  return yg * Ww + xg;
}

__device__ __forceinline__ float firstlane(float v) {
  return __int_as_float(__builtin_amdgcn_readfirstlane(__float_as_int(v)));
}

// Cross-lane xor-1 / xor-2 on the VALU via DPP quad_perm (no DS pipe).
__device__ __forceinline__ float dpp_xor1(float v) {
  return __int_as_float(__builtin_amdgcn_update_dpp(
      0, __float_as_int(v), 0xB1, 0xF, 0xF, true));
}
__device__ __forceinline__ float dpp_xor2(float v) {
  return __int_as_float(__builtin_amdgcn_update_dpp(
      0, __float_as_int(v), 0x4E, 0xF, 0xF, true));
}
}

__global__ void kdiag(float* __restrict__ out, float v) {
  if (threadIdx.x == 0 && blockIdx.x == 0) out[0] = v;
}

// winners/hdr init. Must COMPLETE before k_mega's scatter atomics -> own
// (small) launch. 2.5 MB of -1 writes.
__global__ void k0_init(int* __restrict__ winners, int* __restrict__ hdr) {
  const int stride = gridDim.x * blockDim.x;
  const int t = blockIdx.x * blockDim.x + threadIdx.x;
  if (t < 8) hdr[t] = 0;
  for (int i = t; i < 2 * Bn * NCELL; i += stride) winners[i] = -1;
}

// MEGA LAUNCH: blocks [0,FILL_B) write the bias canvas (memory-only; its
// write traffic hides under the VALU-bound momfeat blocks that follow).
// Blocks [FILL_B, FILL_B+2*K1B): R8's proven fused pass -- moments + scatter
// + RAW PFN matmul + max-over-points, one pillar per wave-iteration, lane=n.
// xv[c] (loaded once) feeds BOTH the moment accumulators and the matmul.
// Matmul uses RAW weights (no dependency on moments): y chain = exact R0
// fmaf chain; only ymax = max_n y is stored (fmax order-exact); LN+ReLU is
// applied downstream via the monotone identity max_n fma(a,y,cc) =
// fma(a, max_n y, cc) (a<0 via k_negfix). Weights per 8-channel chunk via one
// inline-asm s_load block -> SGPRs (scalar-cache hits); inner loop is pure
// v_fma with one scalar operand. Reduce-scatter max: DPP xor1/xor2 + shfl.
__global__ __launch_bounds__(256) void k_mega(
    const float* __restrict__ sweep, const float* __restrict__ map_in,
    const float* __restrict__ w_s, const float* __restrict__ b_s,
    const float* __restrict__ w_m, const float* __restrict__ b_m,
    const float* __restrict__ b_bb, float* __restrict__ out,
    float* __restrict__ partOut, int* __restrict__ winners,
    float* __restrict__ ymax)
{
  if (blockIdx.x < FILL_B) {
    const int idx = blockIdx.x * 256 + threadIdx.x;
    const int plane = idx / (NCELL / 4);      // b*Co + o
    const float v = b_bb[plane & 63];
    ((float4*)out)[idx] = make_float4(v, v, v, v);
    return;
  }
  __shared__ float red[4][44];
  const int bid  = blockIdx.x - FILL_B;
  const int lane = threadIdx.x & 63;
  const int wv   = threadIdx.x >> 6;
  const int bid2 = bid & (K1B - 1);
  const int inp  = bid / K1B;
  const float* x  = inp ? map_in : sweep;
  const float* w  = inp ? w_m : w_s;
  const float* bb = inp ? b_m : b_s;
  int*   win = winners + inp * Bn * NCELL;
  float* ym  = ymax + (size_t)inp * NPIL * 64;
  const int gw   = (bid2 * 256 + (int)threadIdx.x) >> 6;
  const int nw   = (K1B * 256) >> 6;

  float sacc[8];
  float macc[36];
#pragma unroll
  for (int i = 0; i < 8; ++i) sacc[i] = 0.f;
#pragma unroll
  for (int i = 0; i < 36; ++i) macc[i] = 0.f;

  const int l0 = lane & 1, l1 = (lane >> 1) & 1, l2 = (lane >> 2) & 1;

  for (int pp = gw; pp < NPIL; pp += nw) {
    const int b = pp / Pn;
    const int p = pp - b * Pn;
    const float* xb = x + (size_t)b * Cin * CHW + (size_t)p * Nn + lane;
    float xv[Cin];
#pragma unroll
    for (int c = 0; c < Cin; ++c) xv[c] = xb[(size_t)c * CHW];

    // ---- moments (unchanged chains -> bit-identical moments) ----
#pragma unroll
    for (int c = 0; c < Cin; ++c) sacc[c] += xv[c];
    {
      int k = 0;
#pragma unroll
      for (int i = 0; i < 8; ++i)
#pragma unroll
        for (int j = i; j < 8; ++j) { macc[k] = fmaf(xv[i], xv[j], macc[k]); ++k; }
    }

    // ---- fused scatter ----
    const float xc = firstlane(xv[0]);
    if (xc != 0.0f) {
      const float yc = firstlane(xv[1]);
      if (lane == 0) atomicMax(&win[b * NCELL + cell_of(xc, yc)], p);
    }

    // ---- raw matmul + max-over-points ----
    float res = 0.f;
#pragma unroll
    for (int g = 0; g < 8; ++g) {
      f32x8_t wr0, wr1, wr2, wr3, wr4, wr5, wr6, wr7, b8;
      asm("s_load_dwordx8 %0, %9, 0x0\n\t"
          "s_load_dwordx8 %1, %9, 0x20\n\t"
          "s_load_dwordx8 %2, %9, 0x40\n\t"
          "s_load_dwordx8 %3, %9, 0x60\n\t"
          "s_load_dwordx8 %4, %9, 0x80\n\t"
          "s_load_dwordx8 %5, %9, 0xA0\n\t"
          "s_load_dwordx8 %6, %9, 0xC0\n\t"
          "s_load_dwordx8 %7, %9, 0xE0\n\t"
          "s_load_dwordx8 %8, %10, 0x0\n\t"
          "s_waitcnt lgkmcnt(0)"
          : "=&s"(wr0), "=&s"(wr1), "=&s"(wr2), "=&s"(wr3), "=&s"(wr4),
            "=&s"(wr5), "=&s"(wr6), "=&s"(wr7), "=&s"(b8)
          : "s"(w + g * 64), "s"(bb + g * 8));

      float z[8];
#define PFN_ROW(J, WR)                                                        \
      {                                                                       \
        float y = b8[J];                                                      \
        _Pragma("unroll")                                                     \
        for (int c = 0; c < Cin; ++c) y = fmaf(WR[c], xv[c], y);              \
        z[J] = y;                                                             \
      }
      PFN_ROW(0, wr0) PFN_ROW(1, wr1) PFN_ROW(2, wr2) PFN_ROW(3, wr3)
      PFN_ROW(4, wr4) PFN_ROW(5, wr5) PFN_ROW(6, wr6) PFN_ROW(7, wr7)
#undef PFN_ROW

      // reduce-scatter max (proven tree; fmax is order-exact)
      float t0[4];
#pragma unroll
      for (int i = 0; i < 4; ++i) {
        const float send = l0 ? z[2 * i] : z[2 * i + 1];
        const float keep = l0 ? z[2 * i + 1] : z[2 * i];
        t0[i] = fmaxf(keep, dpp_xor1(send));
      }
      float t1[2];
#pragma unroll
      for (int i = 0; i < 2; ++i) {
        const float send = l1 ? t0[2 * i] : t0[2 * i + 1];
        const float keep = l1 ? t0[2 * i + 1] : t0[2 * i];
        t1[i] = fmaxf(keep, dpp_xor2(send));
      }
      {
        const float send = l2 ? t1[0] : t1[1];
        const float keep = l2 ? t1[1] : t1[0];
        float v = fmaxf(keep, __shfl_xor(send, 4, 64));
        v = fmaxf(v, __shfl_xor(v, 8, 64));
        v = fmaxf(v, __shfl_xor(v, 16, 64));
        v = fmaxf(v, __shfl_xor(v, 32, 64));
        if ((lane >> 3) == g) res = v;
      }
    }
    ym[(size_t)pp * 64 + lane] = res;   // RAW ymax (affine+relu downstream)
  }

  // ---- moment partial reduction (unchanged) ----
#pragma unroll
  for (int k = 0; k < 44; ++k) {
    float v = (k < 8) ? sacc[k] : macc[k - 8];
#pragma unroll
    for (int off = 32; off > 0; off >>= 1) v += __shfl_down(v, off, 64);
    if (lane == 0) red[wv][k] = v;
  }
  __syncthreads();
  if (threadIdx.x < 44) {
    const float s = red[0][threadIdx.x] + red[1][threadIdx.x] +
                    red[2][threadIdx.x] + red[3][threadIdx.x];
    partOut[(size_t)bid2 * 88 + inp * 44 + threadIdx.x] = s;
  }
}

// FUSED reduce + params, single block: threads 0..351 partial-sum the part
// array (component c = tid>>2, quarter q = tid&3) in double; tree over
// quarters; threads 0..127 compute a = gamma/sqrt(var+eps), cc = beta-mean*a
// (R0 form) and publish the a<0 mask to hdr[4..7].
__global__ __launch_bounds__(512) void k1b2_params(
    const float* __restrict__ part,
    const float* __restrict__ w_s, const float* __restrict__ b_s,
    const float* __restrict__ g_s, const float* __restrict__ be_s,
    const float* __restrict__ w_m, const float* __restrict__ b_m,
    const float* __restrict__ g_m, const float* __restrict__ be_m,
    float* __restrict__ par, int* __restrict__ hdr)
{
  __shared__ double sd[88][4];
  __shared__ double smom[88];
  const int tid = threadIdx.x;
  if (tid < 352) {
    const int c = tid >> 2, q = tid & 3;
    double s = 0.0;
    for (int j = 0; j < K1B / 4; ++j)
      s += (double)part[(size_t)(q * (K1B / 4) + j) * 88 + c];
    sd[c][q] = s;
  }
  __syncthreads();
  if (tid < 88)
    smom[tid] = (sd[tid][0] + sd[tid][1]) + (sd[tid][2] + sd[tid][3]);
  __syncthreads();
  if (tid >= 128) return;
  const int inp = tid >> 6, o = tid & 63;
  const double* m = smom + inp * 44;
  const float* w    = (inp ? w_m : w_s) + o * Cin;
  const float bias  = (inp ? b_m : b_s)[o];
  const float gamma = (inp ? g_m : g_s)[o];
  const float beta  = (inp ? be_m : be_s)[o];
  double S[8];
#pragma unroll
  for (int c = 0; c < 8; ++c) S[c] = m[c] / CNTD;
  double mean = (double)bias;
#pragma unroll
  for (int c = 0; c < 8; ++c) mean += (double)w[c] * S[c];
  double var = 0.0;
  int k = 8;
#pragma unroll
  for (int i = 0; i < 8; ++i)
#pragma unroll
    for (int j = i; j < 8; ++j) {
      const double cov = m[k] / CNTD - S[i] * S[j];
      const double ww = (double)w[i] * (double)w[j];
      var += (i == j ? ww : 2.0 * ww) * cov;
      ++k;
    }
  const double a = (double)gamma / sqrt(var + 1e-5);
  const double c = (double)beta - mean * a;
  const float af = (float)a;
  par[inp * 128 + o]      = af;
  par[inp * 128 + 64 + o] = (float)c;
  if (af < 0.f) atomicOr(&hdr[4 + inp * 2 + (o >> 5)], 1 << (o & 31));
}

// MERGED LAUNCH: blocks [0,NEGB) = a<0 fix-up (gamma<0 is a ~10-sigma event;
// instant-exit when the mask is zero, so correctness stays data-independent:
// for flagged channels max fma(a,y,cc) = fma(a, MIN_n y, cc) -> rewrite
// ymax[o] := min_n y). Blocks [NEGB, NEGB+COMPACT_B) = ballot-ordered
// worklist compaction (touches winners/wl only -- disjoint from negfix; the
// part alias under wlS is dead after k1b2_params).
__global__ __launch_bounds__(256) void k_negfix_compact(
    const float* __restrict__ sweep, const float* __restrict__ map_in,
    const float* __restrict__ w_s, const float* __restrict__ b_s,
    const float* __restrict__ w_m, const float* __restrict__ b_m,
    const int* __restrict__ winners, int* __restrict__ hdr,
    int2* __restrict__ wlS, int2* __restrict__ wlM,
    float* __restrict__ ymax)
{
  if (blockIdx.x >= NEGB) {
    // ---- compact branch ----
    __shared__ int cS[4], cM[4];
    __shared__ int baseS, baseM;
    const int t = (blockIdx.x - NEGB) * 256 + threadIdx.x;
    const int lane = threadIdx.x & 63;
    const int wvc  = threadIdx.x >> 6;
    int ps = -1, pm = -1, outbase = 0, b = 0;
    if (t < Bn * NCELL) {
      b = t / NCELL;
      const int hw = t - b * NCELL;
      outbase = b * Co * NCELL + hw;
      ps = winners[t];
      pm = winners[Bn * NCELL + t];
    }
    const unsigned long long ms = __ballot(ps >= 0);
    const unsigned long long mm = __ballot(pm >= 0);
    if (lane == 0) { cS[wvc] = __popcll(ms); cM[wvc] = __popcll(mm); }
    __syncthreads();
    if (threadIdx.x == 0) {
      const int c = cS[0] + cS[1] + cS[2] + cS[3];
      baseS = c ? atomicAdd(&hdr[1], c) : 0;
    } else if (threadIdx.x == 64) {
      const int c = cM[0] + cM[1] + cM[2] + cM[3];
      baseM = c ? atomicAdd(&hdr[2], c) : 0;
    }
    __syncthreads();
    const unsigned long long below = (1ull << lane) - 1ull;
    if (ps >= 0) {
      int off = baseS + __popcll(ms & below);
      for (int w2 = 0; w2 < wvc; ++w2) off += cS[w2];
      wlS[off] = make_int2(outbase, b * Pn + ps);
    }
    if (pm >= 0) {
      int off = baseM + __popcll(mm & below);
      for (int w2 = 0; w2 < wvc; ++w2) off += cM[w2];
      wlM[off] = make_int2(outbase, b * Pn + pm);
    }
    return;
  }

  // ---- negfix branch ----
  const int inp = blockIdx.x & 1;
  const unsigned m0 = (unsigned)hdr[4 + inp * 2];
  const unsigned m1 = (unsigned)hdr[5 + inp * 2];
  if ((m0 | m1) == 0u) return;
  const float* x  = inp ? map_in : sweep;
  const float* w  = inp ? w_m : w_s;
  const float* bb = inp ? b_m : b_s;
  float* ym = ymax + (size_t)inp * NPIL * 64;
  const int lane = threadIdx.x & 63;
  const int wv   = threadIdx.x >> 6;
  const int gw   = (int)(blockIdx.x >> 1) * 4 + wv;
  const int nw   = (NEGB >> 1) * 4;
  for (int pp = gw; pp < NPIL; pp += nw) {
    const int b = pp / Pn;
    const int p = pp - b * Pn;
    const size_t base = (size_t)b * Cin * CHW + (size_t)p * Nn;
    float xv[Cin];
#pragma unroll
    for (int c = 0; c < Cin; ++c) xv[c] = x[base + (size_t)c * CHW + lane];
    for (int half = 0; half < 2; ++half) {
      unsigned m = half ? m1 : m0;
      while (m) {
        const int bit = __ffs(m) - 1;
        m &= m - 1;
        const int o = half * 32 + bit;
        float y = bb[o];
#pragma unroll
        for (int c = 0; c < Cin; ++c) y = fmaf(w[o * Cin + c], xv[c], y);
#pragma unroll
        for (int s = 1; s < 64; s <<= 1) y = fminf(y, __shfl_xor(y, s, 64));
        if (lane == 0) ym[(size_t)pp * 64 + o] = y;
      }
    }
  }
}

// Dense matvec over the compacted worklist, with the LN affine+ReLU applied
// INLINE from ymax: f[o] = relu(fma(a[o], ymax[o], cc[o])) -- identical values
// to the stored-feats variants, then the identical fmaf dot-product chain.
// WHICH=0 (sweep): out = bias + W[:,0:64]·f   (overwrite after fill)
// WHICH=1 (map):   out +=        W[:,64:128]·f (RMW, after WHICH=0);
//                  also carries the occupancy verdict.
// NOTE: the WHICH offset into ymax is applied HERE (ybase) -- the launcher
// must pass the BASE ymax pointer to both instantiations. R11's failure was
// exactly this: the launcher pre-offset ymax for WHICH=1, doubling the
// offset and reading past the ymax region for the map half.
template<int WHICH>
__global__ __launch_bounds__(256) void k_apply(
    const int* __restrict__ hdr, const int2* __restrict__ wl,
    const float* __restrict__ ymax, const float* __restrict__ par,
    const float* __restrict__ w_bb, const float* __restrict__ b_bb,
    float* __restrict__ out)
{
  __shared__ float4 wlds[Co * 16];
  __shared__ float bbb[Co];
  __shared__ float av[Co], cv[Co];
  for (int i = threadIdx.x; i < Co * 16; i += 256)
    wlds[i] = ((const float4*)w_bb)[((i >> 4) << 5) + (WHICH ? 16 : 0) + (i & 15)];
  if (threadIdx.x < Co) {
    bbb[threadIdx.x] = b_bb[threadIdx.x];
    av[threadIdx.x]  = par[WHICH * 128 + threadIdx.x];
    cv[threadIdx.x]  = par[WHICH * 128 + 64 + threadIdx.x];
  }
  __syncthreads();
  const float* ybase = ymax + (size_t)WHICH * NPIL * 64;
  const int cnt = hdr[1 + WHICH];
  for (int i = blockIdx.x * blockDim.x + threadIdx.x; i < cnt;
       i += gridDim.x * blockDim.x) {
    const int2 e = wl[i];
    const float4* yp = (const float4*)(ybase + (size_t)e.y * 64);
    float4 f[16];
#pragma unroll
    for (int k = 0; k < 16; ++k) {
      const float4 ymv = yp[k];
      f[k].x = fmaxf(fmaf(av[4 * k + 0], ymv.x, cv[4 * k + 0]), 0.f);
      f[k].y = fmaxf(fmaf(av[4 * k + 1], ymv.y, cv[4 * k + 1]), 0.f);
      f[k].z = fmaxf(fmaf(av[4 * k + 2], ymv.z, cv[4 * k + 2]), 0.f);
      f[k].w = fmaxf(fmaf(av[4 * k + 3], ymv.w, cv[4 * k + 3]), 0.f);
    }
    float* op = out + e.x;
#pragma unroll 2
    for (int o = 0; o < Co; ++o) {
      float acc = WHICH ? op[(size_t)o * NCELL] : bbb[o];
      const float4* row = &wlds[o * 16];
#pragma unroll
      for (int k = 0; k < 16; ++k) {
        const float4 w4 = row[k];
        acc = fmaf(w4.x, f[k].x, acc); acc = fmaf(w4.y, f[k].y, acc);
        acc = fmaf(w4.z, f[k].z, acc); acc = fmaf(w4.w, f[k].w, acc);
      }
      op[(size_t)o * NCELL] = acc;
    }
  }
  if (WHICH == 1 && blockIdx.x == 0 && threadIdx.x == 0) {
    const int n_occ = hdr[1] + hdr[2];
    if (n_occ < 80000 || n_occ > 96000) out[0] = 1.0e7f + (float)n_occ;
  }
}

extern "C" void kernel_launch(void* const* d_in, const int* in_sizes, int n_in,
                              void* d_out, int out_size, void* d_ws, size_t ws_size,
                              hipStream_t stream)
{
  const float* sweep  = (const float*)d_in[0];
  const float* map_in = (const float*)d_in[1];
  const float* w_s  = (const float*)d_in[2];
  const float* b_s  = (const float*)d_in[3];
  const float* g_s  = (const float*)d_in[4];
  const float* be_s = (const float*)d_in[5];
  const float* w_m  = (const float*)d_in[6];
  const float* b_m  = (const float*)d_in[7];
  const float* g_m  = (const float*)d_in[8];
  const float* be_m = (const float*)d_in[9];
  const float* w_bb = (const float*)d_in[10];
  const float* b_bb = (const float*)d_in[11];
  float* out = (float*)d_out;

  const int exp_sz[12] = {24576000, 24576000, 512, 64, 64, 64, 512, 64, 64, 64, 8192, 64};
  int bad_idx = -1;
  if (n_in != 12) bad_idx = 11;
  else for (int i = 0; i < 12; ++i) if (in_sizes[i] != exp_sz[i]) { bad_idx = i; break; }
  if (bad_idx >= 0) {
    kdiag<<<1, 1, 0, stream>>>(out, 9.0e7f + 1.0e5f * (float)bad_idx);
    return;
  }
  if (ws_size < WS_NEED) {
    kdiag<<<1, 1, 0, stream>>>(out, 8.0e7f);
    return;
  }

  char* ws = (char*)d_ws;
  float*  par     = (float*)(ws + PAR_OFF);
  int*    hdr     = (int*)(ws + HDR_OFF);
  int*    winners = (int*)(ws + WIN_OFF);
  float*  ymax    = (float*)(ws + YMAX_OFF);
  float*  part    = (float*)(ws + PART_OFF);
  int2*   wlS     = (int2*)(ws + WLS_OFF);
  int2*   wlM     = (int2*)(ws + WLM_OFF);

  k0_init<<<512, 256, 0, stream>>>(winners, hdr);
  k_mega<<<FILL_B + 2 * K1B, 256, 0, stream>>>(sweep, map_in, w_s, b_s, w_m, b_m,
                                               b_bb, out, part, winners, ymax);
  k1b2_params<<<1, 512, 0, stream>>>(part, w_s, b_s, g_s, be_s,
                                     w_m, b_m, g_m, be_m, par, hdr);
  k_negfix_compact<<<NEGB + COMPACT_B, 256, 0, stream>>>(
      sweep, map_in, w_s, b_s, w_m, b_m, winners, hdr, wlS, wlM, ymax);
  k_apply<0><<<APPLY_B, 256, 0, stream>>>(hdr, wlS, ymax, par, w_bb, b_bb, out);
  k_apply<1><<<APPLY_B, 256, 0, stream>>>(hdr, wlM, ymax, par, w_bb, b_bb, out);
}

// Round 13
// 294.126 us; speedup vs baseline: 1.1262x; 1.1262x over previous
//
#include <hip/hip_runtime.h>
#include <cfloat>
#include <math.h>

namespace {
constexpr int Bn = 4, Cin = 8, Pn = 12000, Nn = 64, Co = 64, Hh = 282, Ww = 282;
constexpr int NPIL  = Bn * Pn;
constexpr int NCELL = Hh * Ww;
constexpr int CHW   = Pn * Nn;
constexpr double CNTD = (double)Bn * Pn * Nn;
constexpr int K1B = 1024;               // moment blocks per input
constexpr int WL_CAP = 48000;           // max occupied cells per input
constexpr int APPLY_B = (WL_CAP + 255) / 256;
constexpr int FILL_B = (Bn * Co * NCELL / 4) / 256;   // 19881, exact
constexpr int K5B = 2 * NPIL / 4;                     // 24000 k5f blocks
constexpr int COMPACT_B = (Bn * NCELL + 511) / 512;   // 622 (512-thr blocks)

// Workspace layout. part (moment partials, 720896 B) aliases the FEATS
// region: part is written by k_fillmom, read by k1b2c block 0, and dead
// before k5f_feat (a later launch) writes feats. The wl region is NOT
// aliased, so k1b2c's compact blocks can write wlS/wlM concurrently with
// block 0 reading part.
constexpr size_t PAR_OFF  = 0;                          // 2*576 floats = 4608
constexpr size_t HDR_OFF  = 5376;                       // 8 ints
constexpr size_t WLS_OFF  = 8192;                       // WL_CAP int2
constexpr size_t WLM_OFF  = WLS_OFF + (size_t)WL_CAP * 8;    // 392192
constexpr size_t WIN_OFF  = WLM_OFF + (size_t)WL_CAP * 8;    // 776192
constexpr size_t FEAT_OFF = WIN_OFF + (size_t)2 * Bn * NCELL * 4; // 3320960
constexpr size_t PART_OFF = FEAT_OFF;                   // alias (see above)
constexpr size_t WS_NEED  = FEAT_OFF + (size_t)2 * NPIL * 64 * 4; // 27896960

typedef __attribute__((ext_vector_type(8))) float f32x8_t;
typedef __attribute__((ext_vector_type(2))) float f32x2_t;

// Grid mapping matched to XLA's canonicalization: division by 0.16 becomes
// multiplication by the EXACT reciprocal 6.25 (rcp(0.16f) rounds to 6.25f).
// f32-div differs by ~0.3ulp -> O(1) pillars land one cell off (the 2.62 bug).
__device__ __forceinline__ int cell_of(float xc, float yc) {
  int xg = (int)floorf((xc + 22.0f) * 6.25f);
  int yg = (int)floorf((yc + 22.0f) * 6.25f);
  xg = min(max(xg, 0), Ww - 1);
  yg = min(max(yg, 0), Hh - 1);
  return yg * Ww + xg;
}

__device__ __forceinline__ float firstlane(float v) {
  return __int_as_float(__builtin_amdgcn_readfirstlane(__float_as_int(v)));
}

// Cross-lane xor-1 / xor-2 on the VALU via DPP quad_perm (no DS pipe).
__device__ __forceinline__ float dpp_xor1(float v) {
  return __int_as_float(__builtin_amdgcn_update_dpp(
      0, __float_as_int(v), 0xB1, 0xF, 0xF, true));
}
__device__ __forceinline__ float dpp_xor2(float v) {
  return __int_as_float(__builtin_amdgcn_update_dpp(
      0, __float_as_int(v), 0x4E, 0xF, 0xF, true));
}
}

__global__ void kdiag(float* __restrict__ out, float v) {
  if (threadIdx.x == 0 && blockIdx.x == 0) out[0] = v;
}

// winners/hdr init. Must COMPLETE before k_fillmom's scatter atomics -> own
// (small) launch.
__global__ void k0_init(int* __restrict__ winners, int* __restrict__ hdr) {
  const int stride = gridDim.x * blockDim.x;
  const int t = blockIdx.x * blockDim.x + threadIdx.x;
  if (t < 8) hdr[t] = 0;
  for (int i = t; i < 2 * Bn * NCELL; i += stride) winners[i] = -1;
}

// MERGED LAUNCH, moment blocks FIRST: blocks [0, 2*K1B) run the float4-
// vectorized moments + scatter pass (one wave handles FOUR pillars/iter;
// dwordx4 loads move 1KB/wave/instr -- R10's proven ~40us kernel). Blocks
// [2*K1B, +FILL_B) write the bias canvas; placed LAST so the long-running
// moment blocks launch at t=0 and the fill's writes drain during their tail.
// Moment chains are 4-wide fma (order change absorbed by the double-precision
// final reduction). Scatter: lane q*16 holds xc=xv[0].x, yc=xv[1].x of
// pillar p0+q.
__global__ __launch_bounds__(256) void k_fillmom(
    const float* __restrict__ sweep, const float* __restrict__ map_in,
    const float* __restrict__ b_bb, float* __restrict__ out,
    float* __restrict__ partOut, int* __restrict__ winners)
{
  if (blockIdx.x >= 2 * K1B) {
    const int idx = (blockIdx.x - 2 * K1B) * 256 + threadIdx.x;
    const int plane = idx / (NCELL / 4);      // b*Co + o
    const float v = b_bb[plane & 63];
    ((float4*)out)[idx] = make_float4(v, v, v, v);
    return;
  }
  __shared__ float red[4][44];
  const int bid  = blockIdx.x;
  const int lane = threadIdx.x & 63;
  const int wv   = threadIdx.x >> 6;
  const int bid2 = bid & (K1B - 1);
  const int inp  = bid / K1B;
  const float* x = inp ? map_in : sweep;
  int* win = winners + inp * Bn * NCELL;
  const int gw   = (bid2 * 256 + (int)threadIdx.x) >> 6;   // wave 0..4095
  const int nw   = (K1B * 256) >> 6;                        // 4096
  constexpr int NG  = NPIL / 4;                             // 12000 groups
  constexpr int GPB = Pn / 4;                               // 3000 per batch

  float sacc[8];
  float macc[36];
#pragma unroll
  for (int i = 0; i < 8; ++i) sacc[i] = 0.f;
#pragma unroll
  for (int i = 0; i < 36; ++i) macc[i] = 0.f;

  for (int g = gw; g < NG; g += nw) {
    const int b  = g / GPB;
    const int p0 = (g - b * GPB) * 4;
    const float4* xb4 =
        (const float4*)(x + (size_t)b * Cin * CHW + (size_t)p0 * Nn) + lane;
    float4 xv[Cin];
#pragma unroll
    for (int c = 0; c < Cin; ++c) xv[c] = xb4[(size_t)c * (CHW / 4)];
#pragma unroll
    for (int c = 0; c < Cin; ++c)
      sacc[c] += ((xv[c].x + xv[c].y) + (xv[c].z + xv[c].w));
    {
      int k = 0;
#pragma unroll
      for (int i = 0; i < 8; ++i)
#pragma unroll
        for (int j = i; j < 8; ++j) {
          float m = macc[k];
          m = fmaf(xv[i].x, xv[j].x, m);
          m = fmaf(xv[i].y, xv[j].y, m);
          m = fmaf(xv[i].z, xv[j].z, m);
          m = fmaf(xv[i].w, xv[j].w, m);
          macc[k] = m;
          ++k;
        }
    }
    if ((lane & 15) == 0) {
      const float xc = xv[0].x;
      if (xc != 0.0f) {
        const float yc = xv[1].x;
        atomicMax(&win[b * NCELL + cell_of(xc, yc)], p0 + (lane >> 4));
      }
    }
  }

#pragma unroll
  for (int k = 0; k < 44; ++k) {
    float v = (k < 8) ? sacc[k] : macc[k - 8];
#pragma unroll
    for (int off = 32; off > 0; off >>= 1) v += __shfl_down(v, off, 64);
    if (lane == 0) red[wv][k] = v;
  }
  __syncthreads();
  if (threadIdx.x < 44) {
    const float s = red[0][threadIdx.x] + red[1][threadIdx.x] +
                    red[2][threadIdx.x] + red[3][threadIdx.x];
    partOut[(size_t)bid2 * 88 + inp * 44 + threadIdx.x] = s;
  }
}

// MERGED LAUNCH (512 threads): block 0 = fused part-reduce + LN-folded
// params (R10's proven kernel: threads 0..351 partial-sum in double, tree,
// threads 0..127 emit awT[c][o] = a*w[c] (c-major) and zb = beta+a*(bias-mean)).
// Blocks [1, 1+COMPACT_B) = ballot-ordered worklist compaction at 512 threads
// (8 waves/block). No hazard: part aliases FEATS (untouched here); wl region
// is separate.
__global__ __launch_bounds__(512) void k1b2c(
    const float* __restrict__ part,
    const float* __restrict__ w_s, const float* __restrict__ b_s,
    const float* __restrict__ g_s, const float* __restrict__ be_s,
    const float* __restrict__ w_m, const float* __restrict__ b_m,
    const float* __restrict__ g_m, const float* __restrict__ be_m,
    float* __restrict__ par, const int* __restrict__ winners,
    int* __restrict__ hdr, int2* __restrict__ wlS, int2* __restrict__ wlM)
{
  if (blockIdx.x == 0) {
    __shared__ double sd[88][4];
    __shared__ double smom[88];
    const int tid = threadIdx.x;
    if (tid < 352) {
      const int c = tid >> 2, q = tid & 3;
      double s = 0.0;
      for (int j = 0; j < K1B / 4; ++j)
        s += (double)part[(size_t)(q * (K1B / 4) + j) * 88 + c];
      sd[c][q] = s;
    }
    __syncthreads();
    if (tid < 88)
      smom[tid] = (sd[tid][0] + sd[tid][1]) + (sd[tid][2] + sd[tid][3]);
    __syncthreads();
    if (tid >= 128) return;
    const int inp = tid >> 6, o = tid & 63;
    const double* m = smom + inp * 44;
    const float* w    = (inp ? w_m : w_s) + o * Cin;
    const float bias  = (inp ? b_m : b_s)[o];
    const float gamma = (inp ? g_m : g_s)[o];
    const float beta  = (inp ? be_m : be_s)[o];
    double S[8];
#pragma unroll
    for (int c = 0; c < 8; ++c) S[c] = m[c] / CNTD;
    double mean = (double)bias;
#pragma unroll
    for (int c = 0; c < 8; ++c) mean += (double)w[c] * S[c];
    double var = 0.0;
    int k = 8;
#pragma unroll
    for (int i = 0; i < 8; ++i)
#pragma unroll
      for (int j = i; j < 8; ++j) {
        const double cov = m[k] / CNTD - S[i] * S[j];
        const double ww = (double)w[i] * (double)w[j];
        var += (i == j ? ww : 2.0 * ww) * cov;
        ++k;
      }
    const double a = (double)gamma / sqrt(var + 1e-5);
    float* pr = par + inp * 576;
#pragma unroll
    for (int c = 0; c < 8; ++c) pr[c * 64 + o] = (float)(a * (double)w[c]);
    pr[512 + o] = (float)((double)beta + a * ((double)bias - mean));
    return;
  }

  // ---- compact branch (512 threads = 8 waves) ----
  __shared__ int cS[8], cM[8];
  __shared__ int baseS, baseM;
  const int t = (int)(blockIdx.x - 1) * 512 + (int)threadIdx.x;
  const int lane = threadIdx.x & 63;
  const int wvc  = threadIdx.x >> 6;
  int ps = -1, pm = -1, outbase = 0, b = 0;
  if (t < Bn * NCELL) {
    b = t / NCELL;
    const int hw = t - b * NCELL;
    outbase = b * Co * NCELL + hw;
    ps = winners[t];
    pm = winners[Bn * NCELL + t];
  }
  const unsigned long long ms = __ballot(ps >= 0);
  const unsigned long long mm = __ballot(pm >= 0);
  if (lane == 0) { cS[wvc] = __popcll(ms); cM[wvc] = __popcll(mm); }
  __syncthreads();
  if (threadIdx.x == 0) {
    int c = 0;
#pragma unroll
    for (int i = 0; i < 8; ++i) c += cS[i];
    baseS = c ? atomicAdd(&hdr[1], c) : 0;
  } else if (threadIdx.x == 64) {
    int c = 0;
#pragma unroll
    for (int i = 0; i < 8; ++i) c += cM[i];
    baseM = c ? atomicAdd(&hdr[2], c) : 0;
  }
  __syncthreads();
  const unsigned long long below = (1ull << lane) - 1ull;
  if (ps >= 0) {
    int off = baseS + __popcll(ms & below);
    for (int w2 = 0; w2 < wvc; ++w2) off += cS[w2];
    wlS[off] = make_int2(outbase, b * Pn + ps);
  }
  if (pm >= 0) {
    int off = baseM + __popcll(mm & below);
    for (int w2 = 0; w2 < wvc; ++w2) off += cM[w2];
    wlM[off] = make_int2(outbase, b * Pn + pm);
  }
}

// PFN features (the proven R7 142us kernel, standalone): transposed (lane=n),
// channels 8 at a time, SGPR weights via one inline-asm s_load block
// (scalar-cache hits), v_pk_fma_f32 channel pairs (each half = the identical
// fmaf chain), DPP xor1/xor2 + shfl reduce-scatter max (fmax order-exact).
// LN is folded into the weights (awT/zb), so z is post-LN per point and the
// max-then-relu needs no sign fix-up.
__global__ __launch_bounds__(256) void k5f_feat(
    const float* __restrict__ sweep, const float* __restrict__ map_in,
    const float* __restrict__ par, const int* __restrict__ winners,
    float* __restrict__ feats)
{
  const int lane = threadIdx.x & 63;       // = point index n
  const int wv   = __builtin_amdgcn_readfirstlane(threadIdx.x >> 6);
  int pp = blockIdx.x * 4 + wv;
  const int inp = (pp >= NPIL) ? 1 : 0;
  pp -= inp * NPIL;
  const float* x   = inp ? map_in : sweep;
  const float* awT = par + inp * 576;      // [c][64] transposed
  const float* zbp = awT + 512;
  const int*   win = winners + inp * Bn * NCELL;
  float*       ft  = feats + (size_t)inp * NPIL * 64;

  const int b = pp / Pn;
  const int p = pp - b * Pn;
  const size_t base = (size_t)b * Cin * CHW + (size_t)p * Nn;

  float xv[Cin];
#pragma unroll
  for (int c = 0; c < Cin; ++c) xv[c] = x[base + (size_t)c * CHW + lane];

  const float xc0 = firstlane(xv[0]);
  if (xc0 == 0.0f) return;
  const float yc0 = firstlane(xv[1]);
  const int cell = cell_of(xc0, yc0);
  if (win[b * NCELL + cell] != p) return;

  f32x2_t xd[Cin];
#pragma unroll
  for (int c = 0; c < Cin; ++c) xd[c] = (f32x2_t){xv[c], xv[c]};

  const int l0 = lane & 1, l1 = (lane >> 1) & 1, l2 = (lane >> 2) & 1;
  float res = 0.f;
#pragma unroll
  for (int g = 0; g < 8; ++g) {
    f32x8_t wr0, wr1, wr2, wr3, wr4, wr5, wr6, wr7, zb8;
    asm("s_load_dwordx8 %0, %9, 0x0\n\t"
        "s_load_dwordx8 %1, %9, 0x100\n\t"
        "s_load_dwordx8 %2, %9, 0x200\n\t"
        "s_load_dwordx8 %3, %9, 0x300\n\t"
        "s_load_dwordx8 %4, %9, 0x400\n\t"
        "s_load_dwordx8 %5, %9, 0x500\n\t"
        "s_load_dwordx8 %6, %9, 0x600\n\t"
        "s_load_dwordx8 %7, %9, 0x700\n\t"
        "s_load_dwordx8 %8, %10, 0x0\n\t"
        "s_waitcnt lgkmcnt(0)"
        : "=&s"(wr0), "=&s"(wr1), "=&s"(wr2), "=&s"(wr3), "=&s"(wr4),
          "=&s"(wr5), "=&s"(wr6), "=&s"(wr7), "=&s"(zb8)
        : "s"(awT + g * 8), "s"(zbp + g * 8));

    f32x2_t y0 = {zb8[0], zb8[1]};
    f32x2_t y1 = {zb8[2], zb8[3]};
    f32x2_t y2 = {zb8[4], zb8[5]};
    f32x2_t y3 = {zb8[6], zb8[7]};
#define CH(C, W)                                                              \
    {                                                                         \
      f32x2_t wpa = {W[0], W[1]}, wpb = {W[2], W[3]};                         \
      f32x2_t wpc = {W[4], W[5]}, wpd = {W[6], W[7]};                         \
      asm("v_pk_fma_f32 %0, %1, %2, %0" : "+v"(y0) : "s"(wpa), "v"(xd[C]));   \
      asm("v_pk_fma_f32 %0, %1, %2, %0" : "+v"(y1) : "s"(wpb), "v"(xd[C]));   \
      asm("v_pk_fma_f32 %0, %1, %2, %0" : "+v"(y2) : "s"(wpc), "v"(xd[C]));   \
      asm("v_pk_fma_f32 %0, %1, %2, %0" : "+v"(y3) : "s"(wpd), "v"(xd[C]));   \
    }
    CH(0, wr0) CH(1, wr1) CH(2, wr2) CH(3, wr3)
    CH(4, wr4) CH(5, wr5) CH(6, wr6) CH(7, wr7)
#undef CH
    float z[8] = {y0[0], y0[1], y1[0], y1[1], y2[0], y2[1], y3[0], y3[1]};

    float t0[4];
#pragma unroll
    for (int i = 0; i < 4; ++i) {
      const float send = l0 ? z[2 * i] : z[2 * i + 1];
      const float keep = l0 ? z[2 * i + 1] : z[2 * i];
      t0[i] = fmaxf(keep, dpp_xor1(send));
    }
    float t1[2];
#pragma unroll
    for (int i = 0; i < 2; ++i) {
      const float send = l1 ? t0[2 * i] : t0[2 * i + 1];
      const float keep = l1 ? t0[2 * i + 1] : t0[2 * i];
      t1[i] = fmaxf(keep, dpp_xor2(send));
    }
    {
      const float send = l2 ? t1[0] : t1[1];
      const float keep = l2 ? t1[1] : t1[0];
      float v = fmaxf(keep, __shfl_xor(send, 4, 64));
      v = fmaxf(v, __shfl_xor(v, 8, 64));
      v = fmaxf(v, __shfl_xor(v, 16, 64));
      v = fmaxf(v, __shfl_xor(v, 32, 64));
      if ((lane >> 3) == g) res = v;
    }
  }
  ft[(size_t)pp * 64 + lane] = fmaxf(res, 0.f);
}

// Dense matvec over the compacted worklist (split pair).
// WHICH=0 (sweep): out[o] = bias[o] + W[:,0:64]·f   (overwrite after fill)
// WHICH=1 (map):   out[o] +=          W[:,64:128]·f (RMW, after WHICH=0);
//                  also carries the occupancy verdict.
// CONVENTION: the launcher passes the PRE-OFFSET feats pointer (feats for
// WHICH=0, feats + NPIL*64 for WHICH=1); the template does NOT offset.
template<int WHICH>
__global__ __launch_bounds__(256) void k_apply(
    const int* __restrict__ hdr, const int2* __restrict__ wl,
    const float* __restrict__ feats, const float* __restrict__ w_bb,
    const float* __restrict__ b_bb, float* __restrict__ out)
{
  __shared__ float4 wlds[Co * 16];
  __shared__ float bbb[Co];
  for (int i = threadIdx.x; i < Co * 16; i += 256)
    wlds[i] = ((const float4*)w_bb)[((i >> 4) << 5) + (WHICH ? 16 : 0) + (i & 15)];
  if (threadIdx.x < Co) bbb[threadIdx.x] = b_bb[threadIdx.x];
  __syncthreads();
  const int cnt = hdr[1 + WHICH];
  for (int i = blockIdx.x * blockDim.x + threadIdx.x; i < cnt;
       i += gridDim.x * blockDim.x) {
    const int2 e = wl[i];
    const float4* fp = (const float4*)(feats + (size_t)e.y * 64);
    float4 f[16];
#pragma unroll
    for (int k = 0; k < 16; ++k) f[k] = fp[k];
    float* op = out + e.x;
#pragma unroll 2
    for (int o = 0; o < Co; ++o) {
      float acc = WHICH ? op[(size_t)o * NCELL] : bbb[o];
      const float4* row = &wlds[o * 16];
#pragma unroll
      for (int k = 0; k < 16; ++k) {
        const float4 w4 = row[k];
        acc = fmaf(w4.x, f[k].x, acc); acc = fmaf(w4.y, f[k].y, acc);
        acc = fmaf(w4.z, f[k].z, acc); acc = fmaf(w4.w, f[k].w, acc);
      }
      op[(size_t)o * NCELL] = acc;
    }
  }
  if (WHICH == 1 && blockIdx.x == 0 && threadIdx.x == 0) {
    const int n_occ = hdr[1] + hdr[2];
    if (n_occ < 80000 || n_occ > 96000) out[0] = 1.0e7f + (float)n_occ;
  }
}

extern "C" void kernel_launch(void* const* d_in, const int* in_sizes, int n_in,
                              void* d_out, int out_size, void* d_ws, size_t ws_size,
                              hipStream_t stream)
{
  const float* sweep  = (const float*)d_in[0];
  const float* map_in = (const float*)d_in[1];
  const float* w_s  = (const float*)d_in[2];
  const float* b_s  = (const float*)d_in[3];
  const float* g_s  = (const float*)d_in[4];
  const float* be_s = (const float*)d_in[5];
  const float* w_m  = (const float*)d_in[6];
  const float* b_m  = (const float*)d_in[7];
  const float* g_m  = (const float*)d_in[8];
  const float* be_m = (const float*)d_in[9];
  const float* w_bb = (const float*)d_in[10];
  const float* b_bb = (const float*)d_in[11];
  float* out = (float*)d_out;

  const int exp_sz[12] = {24576000, 24576000, 512, 64, 64, 64, 512, 64, 64, 64, 8192, 64};
  int bad_idx = -1;
  if (n_in != 12) bad_idx = 11;
  else for (int i = 0; i < 12; ++i) if (in_sizes[i] != exp_sz[i]) { bad_idx = i; break; }
  if (bad_idx >= 0) {
    kdiag<<<1, 1, 0, stream>>>(out, 9.0e7f + 1.0e5f * (float)bad_idx);
    return;
  }
  if (ws_size < WS_NEED) {
    kdiag<<<1, 1, 0, stream>>>(out, 8.0e7f);
    return;
  }

  char* ws = (char*)d_ws;
  float*  par     = (float*)(ws + PAR_OFF);
  int*    hdr     = (int*)(ws + HDR_OFF);
  int*    winners = (int*)(ws + WIN_OFF);
  float*  feats   = (float*)(ws + FEAT_OFF);
  float*  part    = (float*)(ws + PART_OFF);
  int2*   wlS     = (int2*)(ws + WLS_OFF);
  int2*   wlM     = (int2*)(ws + WLM_OFF);

  k0_init<<<512, 256, 0, stream>>>(winners, hdr);
  k_fillmom<<<2 * K1B + FILL_B, 256, 0, stream>>>(sweep, map_in, b_bb, out,
                                                  part, winners);
  k1b2c<<<1 + COMPACT_B, 512, 0, stream>>>(part, w_s, b_s, g_s, be_s,
                                           w_m, b_m, g_m, be_m, par,
                                           winners, hdr, wlS, wlM);
  k5f_feat<<<K5B, 256, 0, stream>>>(sweep, map_in, par, winners, feats);
  k_apply<0><<<APPLY_B, 256, 0, stream>>>(hdr, wlS, feats, w_bb, b_bb, out);
  k_apply<1><<<APPLY_B, 256, 0, stream>>>(hdr, wlM, feats + (size_t)NPIL * 64,
                                          w_bb, b_bb, out);
}